// Round 3
// baseline (1082.508 us; speedup 1.0000x reference)
//
#include <hip/hip_runtime.h>
#include <hip/hip_bf16.h>
#include <math.h>

#define N_NODES 100000
#define N_EDGES 500000
#define MEM 128
#define IN_DIM 256
#define EDGEF 64
#define D_EDGE 128
#define EPSILON 0.1f
#define GAMMA 0.1f
#define SCALE 0.08838834764831845f  // 1/sqrt(128)

#define NPB 8     // nodes per block in k_final
#define NT 32     // nodes per block in k_node_proj (100000/32 = 3125)
#define XP 264    // padded LDS row for x bf16 tile (shorts)
#define HP 136    // padded LDS row for h bf16 tile (shorts)
#define ET 64     // edges per block in k_edge_all
#define EA_LD 136 // padded LDS row for bf16 edge tiles

typedef __attribute__((ext_vector_type(8))) short bf16x8;
typedef __attribute__((ext_vector_type(4))) float f32x4;

__device__ __forceinline__ short f2bs(float f) {
    __hip_bfloat16 b = __float2bfloat16(f);
    return *(short*)&b;
}
__device__ __forceinline__ float bs2f(short s) {
    __hip_bfloat16 b = *(__hip_bfloat16*)&s;
    return __bfloat162float(b);
}
// unpack 2 bf16 (packed in a uint) to floats — exact, 2 VALU ops
__device__ __forceinline__ float2 up2(unsigned int u) {
    float2 r;
    r.x = __uint_as_float(u << 16);
    r.y = __uint_as_float(u & 0xffff0000u);
    return r;
}

// Abuf = W_anti - W_anti^T - gamma*I; bf16 copies of We, Wq, Wk, Wv;
// hi/lo bf16 split of W_enc.
__global__ void k_prep(const float* __restrict__ W_anti, const float* __restrict__ We,
                       const float* __restrict__ W_enc,
                       const float* __restrict__ Wq, const float* __restrict__ Wk,
                       const float* __restrict__ Wv,
                       float* __restrict__ Abuf, unsigned short* __restrict__ Web,
                       unsigned short* __restrict__ WencH, unsigned short* __restrict__ WencL,
                       unsigned short* __restrict__ Wqb, unsigned short* __restrict__ Wkb,
                       unsigned short* __restrict__ Wvb) {
    int idx = blockIdx.x * blockDim.x + threadIdx.x;  // 0..32767
    float w = W_enc[idx];
    short hi = f2bs(w);
    WencH[idx] = (unsigned short)hi;
    WencL[idx] = (unsigned short)f2bs(w - bs2f(hi));
    if (idx < 16384) {
        int m = idx >> 7, d = idx & 127;
        float a = W_anti[m * 128 + d] - W_anti[d * 128 + m];
        if (m == d) a -= GAMMA;
        Abuf[idx] = a;
        Web[idx] = (unsigned short)f2bs(We[idx]);
        Wqb[idx] = (unsigned short)f2bs(Wq[idx]);
        Wkb[idx] = (unsigned short)f2bs(Wk[idx]);
        Wvb[idx] = (unsigned short)f2bs(Wv[idx]);
    }
}

// MFMA node projections. h = x@W_enc^T + b_enc via split-precision bf16
// (x_hi*W_hi + x_lo*W_hi + x_hi*W_lo ~ fp32 accuracy — h feeds out undamped).
// q,k,v = h@W^T + b via plain bf16, STORED AS BF16 (halves edge-phase gather
// traffic; errors damped by softmax normalization + eps*tanh downstream).
__global__ __launch_bounds__(256) void k_node_proj(
    const float* __restrict__ x,
    const float* __restrict__ b_enc, const float* __restrict__ bq,
    const float* __restrict__ bk, const float* __restrict__ bv,
    const unsigned short* __restrict__ WencH, const unsigned short* __restrict__ WencL,
    const unsigned short* __restrict__ Wqb, const unsigned short* __restrict__ Wkb,
    const unsigned short* __restrict__ Wvb,
    float* __restrict__ h, unsigned short* __restrict__ q,
    unsigned short* __restrict__ k, unsigned short* __restrict__ v)
{
    __shared__ short xhi[NT][XP];
    __shared__ short xlo[NT][XP];
    __shared__ short hb[NT][HP];
    const int tid = threadIdx.x;
    const int n0 = blockIdx.x * NT;

    // stage x tile -> hi/lo bf16 LDS
    {
        int r = tid >> 3, seg = tid & 7;  // 32 rows x 8 segs of 32 cols
        const float4* xp = (const float4*)(x + (size_t)(n0 + r) * IN_DIM + seg * 32);
        unsigned int* dh = (unsigned int*)&xhi[r][seg * 32];
        unsigned int* dl = (unsigned int*)&xlo[r][seg * 32];
#pragma unroll
        for (int i = 0; i < 8; i++) {
            float4 a = xp[i];
            float fs[4] = {a.x, a.y, a.z, a.w};
            unsigned short h2[4], l2[4];
#pragma unroll
            for (int j = 0; j < 4; j++) {
                short hbit = f2bs(fs[j]);
                h2[j] = (unsigned short)hbit;
                l2[j] = (unsigned short)f2bs(fs[j] - bs2f(hbit));
            }
            dh[2 * i]     = h2[0] | ((unsigned int)h2[1] << 16);
            dh[2 * i + 1] = h2[2] | ((unsigned int)h2[3] << 16);
            dl[2 * i]     = l2[0] | ((unsigned int)l2[1] << 16);
            dl[2 * i + 1] = l2[2] | ((unsigned int)l2[3] << 16);
        }
    }
    __syncthreads();

    const int wave = tid >> 6, lane = tid & 63;
    const int quad = lane >> 4, l16 = lane & 15;
    const int mt = wave & 1;       // 16-node half
    const int nh = wave >> 1;      // 64-col half

    // h: 3-term split-precision MFMA over K=256
    f32x4 acc[4];
#pragma unroll
    for (int i = 0; i < 4; i++) acc[i] = (f32x4){0.f, 0.f, 0.f, 0.f};
#pragma unroll
    for (int ko = 0; ko < 8; ko++) {
        bf16x8 ah = *(const bf16x8*)&xhi[mt * 16 + l16][ko * 32 + quad * 8];
        bf16x8 al = *(const bf16x8*)&xlo[mt * 16 + l16][ko * 32 + quad * 8];
#pragma unroll
        for (int i = 0; i < 4; i++) {
            size_t boff = (size_t)(nh * 64 + i * 16 + l16) * IN_DIM + ko * 32 + quad * 8;
            bf16x8 bh = *(const bf16x8*)(WencH + boff);
            bf16x8 bl = *(const bf16x8*)(WencL + boff);
            acc[i] = __builtin_amdgcn_mfma_f32_16x16x32_bf16(ah, bh, acc[i], 0, 0, 0);
            acc[i] = __builtin_amdgcn_mfma_f32_16x16x32_bf16(al, bh, acc[i], 0, 0, 0);
            acc[i] = __builtin_amdgcn_mfma_f32_16x16x32_bf16(ah, bl, acc[i], 0, 0, 0);
        }
    }
#pragma unroll
    for (int i = 0; i < 4; i++) {
        int col = nh * 64 + i * 16 + l16;
        float be = b_enc[col];
#pragma unroll
        for (int r = 0; r < 4; r++) {
            int row = mt * 16 + quad * 4 + r;
            float hv = acc[i][r] + be;
            h[(size_t)(n0 + row) * MEM + col] = hv;
            hb[row][col] = f2bs(hv);
        }
    }
    __syncthreads();

#define QKV(Wb, BIAS, OUT)                                                        \
    {                                                                             \
        f32x4 a2[4];                                                              \
        for (int i = 0; i < 4; i++) a2[i] = (f32x4){0.f, 0.f, 0.f, 0.f};          \
        for (int ko = 0; ko < 4; ko++) {                                          \
            bf16x8 a = *(const bf16x8*)&hb[mt * 16 + l16][ko * 32 + quad * 8];    \
            for (int i = 0; i < 4; i++) {                                         \
                size_t boff = (size_t)(nh * 64 + i * 16 + l16) * MEM              \
                            + ko * 32 + quad * 8;                                 \
                bf16x8 b = *(const bf16x8*)(Wb + boff);                           \
                a2[i] = __builtin_amdgcn_mfma_f32_16x16x32_bf16(a, b, a2[i], 0, 0, 0); \
            }                                                                     \
        }                                                                         \
        for (int i = 0; i < 4; i++) {                                             \
            int col = nh * 64 + i * 16 + l16;                                     \
            float bb = BIAS[col];                                                 \
            for (int r = 0; r < 4; r++) {                                         \
                int row = mt * 16 + quad * 4 + r;                                 \
                OUT[(size_t)(n0 + row) * MEM + col] =                             \
                    (unsigned short)f2bs(a2[i][r] + bb);                          \
            }                                                                     \
        }                                                                         \
    }
    QKV(Wqb, bq, q)
    QKV(Wkb, bk, k)
    QKV(Wvb, bv, v)
#undef QKV
}

// One pass over 64 edges per block: build edge_attr (bf16 LDS), e_proj via
// MFMA with B-fragments read directly from global Web (L1/L2-resident),
// ep stored back as BF16 into the SAME LDS buffer (~18KB -> 8 blocks/CU).
// Tail: ONE WAVE PER EDGE — lane l owns dims {2l, 2l+1}; q/k/v gathered as
// packed bf16 (one uint per array per edge: halves fetch bytes AND footprint
// vs fp32 -> better L2 hit-rate at 8 blocks/CU); full-wave butterfly shfl_xor
// reduction for alpha; __expf; fp32 atomicAdd into agg/denom.
__global__ __launch_bounds__(256, 8) void k_edge_all(
    const int* __restrict__ ei, const float* __restrict__ last_update,
    const float* __restrict__ t, const float* __restrict__ msg,
    const float* __restrict__ w_time, const float* __restrict__ b_time,
    const unsigned short* __restrict__ Web,
    const unsigned short* __restrict__ q, const unsigned short* __restrict__ k,
    const unsigned short* __restrict__ v,
    float* __restrict__ agg, float* __restrict__ denom)
{
    __shared__ short sE[ET][EA_LD];   // bf16 edge_attr, then overwritten with bf16 ep
    __shared__ int s_src[ET], s_dst[ET];
    __shared__ float s_rel[ET];

    const int tid = threadIdx.x;
    const size_t e0 = (size_t)blockIdx.x * ET;

    if (tid < ET) {
        size_t e = e0 + tid;
        if (e < N_EDGES) {
            int sn = ei[e];
            s_src[tid] = sn;
            s_dst[tid] = ei[N_EDGES + e];
            s_rel[tid] = fabsf(last_update[sn] - t[e]);
        } else {
            s_src[tid] = 0; s_dst[tid] = 0; s_rel[tid] = 0.f;
        }
    }
    __syncthreads();

    // stage edge_attr: thread handles edge j = tid>>2, 32 cols (seg = tid&3)
    {
        int j = tid >> 2, seg = tid & 3, k0 = seg * 32;
        size_t e = e0 + j;
        bool valid = (e < N_EDGES);
        float vals[32];
        if (seg < 2) {
            if (valid) {
                const float4* mp = (const float4*)(msg + e * EDGEF + k0);
#pragma unroll
                for (int i = 0; i < 8; i++) {
                    float4 a = mp[i];
                    vals[4 * i] = a.x; vals[4 * i + 1] = a.y;
                    vals[4 * i + 2] = a.z; vals[4 * i + 3] = a.w;
                }
            } else {
#pragma unroll
                for (int i = 0; i < 32; i++) vals[i] = 0.f;
            }
        } else {
            int td = k0 - 64;
            float rel = s_rel[j];
            const float4* wtp = (const float4*)(w_time + td);
            const float4* btp = (const float4*)(b_time + td);
#pragma unroll
            for (int i = 0; i < 8; i++) {
                float4 wt = wtp[i];
                float4 bt = btp[i];
                vals[4 * i]     = valid ? __cosf(rel * wt.x + bt.x) : 0.f;
                vals[4 * i + 1] = valid ? __cosf(rel * wt.y + bt.y) : 0.f;
                vals[4 * i + 2] = valid ? __cosf(rel * wt.z + bt.z) : 0.f;
                vals[4 * i + 3] = valid ? __cosf(rel * wt.w + bt.w) : 0.f;
            }
        }
        unsigned int* dp = (unsigned int*)&sE[j][k0];
#pragma unroll
        for (int i = 0; i < 16; i++) {
            unsigned int lo = (unsigned short)f2bs(vals[2 * i]);
            unsigned int hi = (unsigned short)f2bs(vals[2 * i + 1]);
            dp[i] = lo | (hi << 16);
        }
    }
    __syncthreads();

    const int wave = tid >> 6, lane = tid & 63;
    const int quad = lane >> 4, l16 = lane & 15;

    // MFMA: wave w computes ep rows w*16..w*16+15 (its OWN edges), all 128 cols.
    // B-fragments straight from global Web (32KB, cache-resident).
    f32x4 acc[8];
#pragma unroll
    for (int i = 0; i < 8; i++) acc[i] = (f32x4){0.f, 0.f, 0.f, 0.f};
#pragma unroll
    for (int ko = 0; ko < 4; ko++) {
        bf16x8 a = *(const bf16x8*)&sE[wave * 16 + l16][ko * 32 + quad * 8];
#pragma unroll
        for (int i = 0; i < 8; i++) {
            bf16x8 b = *(const bf16x8*)(Web + (size_t)(i * 16 + l16) * D_EDGE + ko * 32 + quad * 8);
            acc[i] = __builtin_amdgcn_mfma_f32_16x16x32_bf16(a, b, acc[i], 0, 0, 0);
        }
    }
    __syncthreads();   // all sE(edge_attr) reads complete before overwrite with ep
#pragma unroll
    for (int i = 0; i < 8; i++)
#pragma unroll
        for (int r = 0; r < 4; r++)
            sE[wave * 16 + quad * 4 + r][i * 16 + l16] = f2bs(acc[i][r]);
    __syncthreads();

    // Tail: wave w owns edges w*16..w*16+15. Lane l handles dims {2l, 2l+1}.
    // N_EDGES%16==0 and ranges 16-aligned -> validity per-wave all-or-nothing.
    const int base = wave * 16;
    const int d2 = lane * 2;
    if (e0 + base < N_EDGES) {
        for (int jj = 0; jj < 16; jj += 2) {
            int ja = base + jj, jb = ja + 1;
            int sa = s_src[ja], da = s_dst[ja];
            int sb = s_src[jb], db = s_dst[jb];
            float2 epa = up2(*(const unsigned int*)&sE[ja][d2]);
            float2 epb = up2(*(const unsigned int*)&sE[jb][d2]);
            float2 qa = up2(*(const unsigned int*)(q + (size_t)da * MEM + d2));
            float2 qb2 = up2(*(const unsigned int*)(q + (size_t)db * MEM + d2));
            float2 ka = up2(*(const unsigned int*)(k + (size_t)sa * MEM + d2));
            float2 kb2 = up2(*(const unsigned int*)(k + (size_t)sb * MEM + d2));
            float ka0 = ka.x + epa.x, ka1 = ka.y + epa.y;
            float kb0 = kb2.x + epb.x, kb1 = kb2.y + epb.y;
            float pa = qa.x * ka0 + qa.y * ka1;
            float pb = qb2.x * kb0 + qb2.y * kb1;
#pragma unroll
            for (int off = 1; off < 64; off <<= 1) {
                pa += __shfl_xor(pa, off, 64);
                pb += __shfl_xor(pb, off, 64);
            }
            float exa = __expf(pa * SCALE);
            float exb = __expf(pb * SCALE);
            float2 va = up2(*(const unsigned int*)(v + (size_t)sa * MEM + d2));
            float2 vb = up2(*(const unsigned int*)(v + (size_t)sb * MEM + d2));
            float va0 = va.x + epa.x, va1 = va.y + epa.y;
            float vb0 = vb.x + epb.x, vb1 = vb.y + epb.y;
            atomicAdd(&agg[(size_t)da * MEM + d2],     exa * va0);
            atomicAdd(&agg[(size_t)da * MEM + d2 + 1], exa * va1);
            atomicAdd(&agg[(size_t)db * MEM + d2],     exb * vb0);
            atomicAdd(&agg[(size_t)db * MEM + d2 + 1], exb * vb1);
            if (lane == 0) {
                atomicAdd(&denom[da], exa);
                atomicAdd(&denom[db], exb);
            }
        }
    }
}

__global__ __launch_bounds__(128) void k_final(
    const float* __restrict__ h, const float* __restrict__ agg,
    const float* __restrict__ denom, const float* __restrict__ Abuf,
    const float* __restrict__ b_anti, float* __restrict__ out)
{
    __shared__ float hsh[NPB][MEM];
    const int m = threadIdx.x;
    const int n0 = blockIdx.x * NPB;
    for (int j = 0; j < NPB; j++) hsh[j][m] = h[(size_t)(n0 + j) * MEM + m];
    __syncthreads();
    float acc[NPB];
    float ba = b_anti[m];
    for (int j = 0; j < NPB; j++) {
        float dn = denom[n0 + j] + 1e-16f;
        acc[j] = ba + agg[(size_t)(n0 + j) * MEM + m] / dn;
    }
    const float4* A4 = (const float4*)(Abuf + (size_t)m * MEM);
    for (int d4 = 0; d4 < MEM / 4; d4++) {
        float4 w = A4[d4];
        int d = d4 * 4;
        for (int j = 0; j < NPB; j++)
            acc[j] += w.x * hsh[j][d] + w.y * hsh[j][d + 1] + w.z * hsh[j][d + 2] + w.w * hsh[j][d + 3];
    }
    for (int j = 0; j < NPB; j++) {
        float hv = hsh[j][m] + EPSILON * tanhf(acc[j]);
        out[(size_t)(n0 + j) * MEM + m] = tanhf(hv);
    }
}

extern "C" void kernel_launch(void* const* d_in, const int* in_sizes, int n_in,
                              void* d_out, int out_size, void* d_ws, size_t ws_size,
                              hipStream_t stream) {
    const float* x          = (const float*)d_in[0];
    const float* last_update= (const float*)d_in[1];
    const int*   ei         = (const int*)  d_in[2];
    const float* t          = (const float*)d_in[3];
    const float* msg        = (const float*)d_in[4];
    const float* w_time     = (const float*)d_in[5];
    const float* b_time     = (const float*)d_in[6];
    const float* W_enc      = (const float*)d_in[7];
    const float* b_enc      = (const float*)d_in[8];
    const float* Wq         = (const float*)d_in[9];
    const float* bq         = (const float*)d_in[10];
    const float* Wk         = (const float*)d_in[11];
    const float* bk         = (const float*)d_in[12];
    const float* Wv         = (const float*)d_in[13];
    const float* bv         = (const float*)d_in[14];
    const float* We         = (const float*)d_in[15];
    const float* W_anti     = (const float*)d_in[16];
    const float* b_anti     = (const float*)d_in[17];
    float* out = (float*)d_out;

    float* ws = (float*)d_ws;
    size_t nm = (size_t)N_NODES * MEM;
    float* h     = ws;                 // N*128 fp32
    float* agg   = h + nm;             // N*128 fp32
    float* denom = agg + nm;           // N fp32
    float* Abuf  = denom + N_NODES;    // 128*128 fp32
    unsigned short* qb    = (unsigned short*)(Abuf + MEM * MEM);  // N*128 bf16
    unsigned short* kb    = qb + nm;        // N*128 bf16
    unsigned short* vb    = kb + nm;        // N*128 bf16
    unsigned short* Web   = vb + nm;        // 16384
    unsigned short* WencH = Web + 16384;    // 32768
    unsigned short* WencL = WencH + 32768;  // 32768
    unsigned short* Wqb   = WencL + 32768;  // 16384
    unsigned short* Wkb   = Wqb + 16384;    // 16384
    unsigned short* Wvb   = Wkb + 16384;    // 16384

    hipMemsetAsync(agg, 0, (nm + N_NODES) * sizeof(float), stream);
    k_prep<<<128, 256, 0, stream>>>(W_anti, We, W_enc, Wq, Wk, Wv,
                                    Abuf, Web, WencH, WencL, Wqb, Wkb, Wvb);

    k_node_proj<<<N_NODES / NT, 256, 0, stream>>>(
        x, b_enc, bq, bk, bv, WencH, WencL, Wqb, Wkb, Wvb, h, qb, kb, vb);

    k_edge_all<<<(N_EDGES + ET - 1) / ET, 256, 0, stream>>>(
        ei, last_update, t, msg, w_time, b_time, Web, qb, kb, vb, agg, denom);

    k_final<<<N_NODES / NPB, 128, 0, stream>>>(h, agg, denom, Abuf, b_anti, out);
}

// Round 4
// 867.459 us; speedup vs baseline: 1.2479x; 1.2479x over previous
//
#include <hip/hip_runtime.h>
#include <hip/hip_bf16.h>
#include <math.h>

#define N_NODES 100000
#define N_EDGES 500000
#define MEM 128
#define IN_DIM 256
#define EDGEF 64
#define D_EDGE 128
#define EPSILON 0.1f
#define GAMMA 0.1f
#define SCALE 0.08838834764831845f  // 1/sqrt(128)

#define NPB 8     // nodes per block in k_final
#define NT 32     // nodes per block in k_node_proj (100000/32 = 3125)
#define XP 264    // padded LDS row for x bf16 tile (shorts)
#define HP 136    // padded LDS row for h bf16 tile (shorts)
#define ET 64     // edges per block in k_edge_all
#define EA_LD 200 // padded LDS row for bf16 edge tile (stride 400B ≡ 4 mod 32
                  // dwords — same conflict-free geometry as 136; sized so LDS
                  // = ~26.4KB -> 6 blocks/CU: measured optimum is between
                  // 4 blocks (under-hides) and 8 blocks (L2 thrash))

typedef __attribute__((ext_vector_type(8))) short bf16x8;
typedef __attribute__((ext_vector_type(4))) float f32x4;

__device__ __forceinline__ short f2bs(float f) {
    __hip_bfloat16 b = __float2bfloat16(f);
    return *(short*)&b;
}
__device__ __forceinline__ float bs2f(short s) {
    __hip_bfloat16 b = *(__hip_bfloat16*)&s;
    return __bfloat162float(b);
}

// Abuf = W_anti - W_anti^T - gamma*I; bf16 copies of We, Wq, Wk, Wv;
// hi/lo bf16 split of W_enc.
__global__ void k_prep(const float* __restrict__ W_anti, const float* __restrict__ We,
                       const float* __restrict__ W_enc,
                       const float* __restrict__ Wq, const float* __restrict__ Wk,
                       const float* __restrict__ Wv,
                       float* __restrict__ Abuf, unsigned short* __restrict__ Web,
                       unsigned short* __restrict__ WencH, unsigned short* __restrict__ WencL,
                       unsigned short* __restrict__ Wqb, unsigned short* __restrict__ Wkb,
                       unsigned short* __restrict__ Wvb) {
    int idx = blockIdx.x * blockDim.x + threadIdx.x;  // 0..32767
    float w = W_enc[idx];
    short hi = f2bs(w);
    WencH[idx] = (unsigned short)hi;
    WencL[idx] = (unsigned short)f2bs(w - bs2f(hi));
    if (idx < 16384) {
        int m = idx >> 7, d = idx & 127;
        float a = W_anti[m * 128 + d] - W_anti[d * 128 + m];
        if (m == d) a -= GAMMA;
        Abuf[idx] = a;
        Web[idx] = (unsigned short)f2bs(We[idx]);
        Wqb[idx] = (unsigned short)f2bs(Wq[idx]);
        Wkb[idx] = (unsigned short)f2bs(Wk[idx]);
        Wvb[idx] = (unsigned short)f2bs(Wv[idx]);
    }
}

// MFMA node projections. h = x@W_enc^T + b_enc via split-precision bf16
// (x_hi*W_hi + x_lo*W_hi + x_hi*W_lo ~ fp32 accuracy — h feeds out undamped).
// q,k,v = h@W^T + b via plain bf16, STORED AS BF16 (halves edge-phase gather
// traffic; errors damped by softmax normalization + eps*tanh downstream).
__global__ __launch_bounds__(256) void k_node_proj(
    const float* __restrict__ x,
    const float* __restrict__ b_enc, const float* __restrict__ bq,
    const float* __restrict__ bk, const float* __restrict__ bv,
    const unsigned short* __restrict__ WencH, const unsigned short* __restrict__ WencL,
    const unsigned short* __restrict__ Wqb, const unsigned short* __restrict__ Wkb,
    const unsigned short* __restrict__ Wvb,
    float* __restrict__ h, unsigned short* __restrict__ q,
    unsigned short* __restrict__ k, unsigned short* __restrict__ v)
{
    __shared__ short xhi[NT][XP];
    __shared__ short xlo[NT][XP];
    __shared__ short hb[NT][HP];
    const int tid = threadIdx.x;
    const int n0 = blockIdx.x * NT;

    // stage x tile -> hi/lo bf16 LDS
    {
        int r = tid >> 3, seg = tid & 7;  // 32 rows x 8 segs of 32 cols
        const float4* xp = (const float4*)(x + (size_t)(n0 + r) * IN_DIM + seg * 32);
        unsigned int* dh = (unsigned int*)&xhi[r][seg * 32];
        unsigned int* dl = (unsigned int*)&xlo[r][seg * 32];
#pragma unroll
        for (int i = 0; i < 8; i++) {
            float4 a = xp[i];
            float fs[4] = {a.x, a.y, a.z, a.w};
            unsigned short h2[4], l2[4];
#pragma unroll
            for (int j = 0; j < 4; j++) {
                short hbit = f2bs(fs[j]);
                h2[j] = (unsigned short)hbit;
                l2[j] = (unsigned short)f2bs(fs[j] - bs2f(hbit));
            }
            dh[2 * i]     = h2[0] | ((unsigned int)h2[1] << 16);
            dh[2 * i + 1] = h2[2] | ((unsigned int)h2[3] << 16);
            dl[2 * i]     = l2[0] | ((unsigned int)l2[1] << 16);
            dl[2 * i + 1] = l2[2] | ((unsigned int)l2[3] << 16);
        }
    }
    __syncthreads();

    const int wave = tid >> 6, lane = tid & 63;
    const int quad = lane >> 4, l16 = lane & 15;
    const int mt = wave & 1;       // 16-node half
    const int nh = wave >> 1;      // 64-col half

    // h: 3-term split-precision MFMA over K=256
    f32x4 acc[4];
#pragma unroll
    for (int i = 0; i < 4; i++) acc[i] = (f32x4){0.f, 0.f, 0.f, 0.f};
#pragma unroll
    for (int ko = 0; ko < 8; ko++) {
        bf16x8 ah = *(const bf16x8*)&xhi[mt * 16 + l16][ko * 32 + quad * 8];
        bf16x8 al = *(const bf16x8*)&xlo[mt * 16 + l16][ko * 32 + quad * 8];
#pragma unroll
        for (int i = 0; i < 4; i++) {
            size_t boff = (size_t)(nh * 64 + i * 16 + l16) * IN_DIM + ko * 32 + quad * 8;
            bf16x8 bh = *(const bf16x8*)(WencH + boff);
            bf16x8 bl = *(const bf16x8*)(WencL + boff);
            acc[i] = __builtin_amdgcn_mfma_f32_16x16x32_bf16(ah, bh, acc[i], 0, 0, 0);
            acc[i] = __builtin_amdgcn_mfma_f32_16x16x32_bf16(al, bh, acc[i], 0, 0, 0);
            acc[i] = __builtin_amdgcn_mfma_f32_16x16x32_bf16(ah, bl, acc[i], 0, 0, 0);
        }
    }
#pragma unroll
    for (int i = 0; i < 4; i++) {
        int col = nh * 64 + i * 16 + l16;
        float be = b_enc[col];
#pragma unroll
        for (int r = 0; r < 4; r++) {
            int row = mt * 16 + quad * 4 + r;
            float hv = acc[i][r] + be;
            h[(size_t)(n0 + row) * MEM + col] = hv;
            hb[row][col] = f2bs(hv);
        }
    }
    __syncthreads();

#define QKV(Wb, BIAS, OUT)                                                        \
    {                                                                             \
        f32x4 a2[4];                                                              \
        for (int i = 0; i < 4; i++) a2[i] = (f32x4){0.f, 0.f, 0.f, 0.f};          \
        for (int ko = 0; ko < 4; ko++) {                                          \
            bf16x8 a = *(const bf16x8*)&hb[mt * 16 + l16][ko * 32 + quad * 8];    \
            for (int i = 0; i < 4; i++) {                                         \
                size_t boff = (size_t)(nh * 64 + i * 16 + l16) * MEM              \
                            + ko * 32 + quad * 8;                                 \
                bf16x8 b = *(const bf16x8*)(Wb + boff);                           \
                a2[i] = __builtin_amdgcn_mfma_f32_16x16x32_bf16(a, b, a2[i], 0, 0, 0); \
            }                                                                     \
        }                                                                         \
        for (int i = 0; i < 4; i++) {                                             \
            int col = nh * 64 + i * 16 + l16;                                     \
            float bb = BIAS[col];                                                 \
            for (int r = 0; r < 4; r++) {                                         \
                int row = mt * 16 + quad * 4 + r;                                 \
                OUT[(size_t)(n0 + row) * MEM + col] =                             \
                    (unsigned short)f2bs(a2[i][r] + bb);                          \
            }                                                                     \
        }                                                                         \
    }
    QKV(Wqb, bq, q)
    QKV(Wkb, bk, k)
    QKV(Wvb, bv, v)
#undef QKV
}

// One pass over 64 edges per block: build edge_attr (bf16 LDS), e_proj via
// MFMA with B-fragments read directly from global Web (L1/L2-resident),
// ep stored back as BF16 into the SAME LDS buffer.
// Tail: ONE WAVE PER EDGE — lane l owns dims {l, l+64}:
//  - gathers are 2B ushort loads (wave = 128B contiguous per instruction)
//  - atomics are lane-contiguous per instruction (wave = 256B contiguous)
//    — the {2l,2l+1} stride-2 layout measurably doubled WRITE_SIZE (R3).
// unsafeAtomicAdd guarantees HW global_atomic_add_f32 (values O(1), no
// denorm risk). No barriers in tail; 2-edge ILP unroll.
__global__ __launch_bounds__(256, 6) void k_edge_all(
    const int* __restrict__ ei, const float* __restrict__ last_update,
    const float* __restrict__ t, const float* __restrict__ msg,
    const float* __restrict__ w_time, const float* __restrict__ b_time,
    const unsigned short* __restrict__ Web,
    const unsigned short* __restrict__ q, const unsigned short* __restrict__ k,
    const unsigned short* __restrict__ v,
    float* __restrict__ agg, float* __restrict__ denom)
{
    __shared__ short sE[ET][EA_LD];   // bf16 edge_attr, then overwritten with bf16 ep
    __shared__ int s_src[ET], s_dst[ET];
    __shared__ float s_rel[ET];

    const int tid = threadIdx.x;
    const size_t e0 = (size_t)blockIdx.x * ET;

    if (tid < ET) {
        size_t e = e0 + tid;
        if (e < N_EDGES) {
            int sn = ei[e];
            s_src[tid] = sn;
            s_dst[tid] = ei[N_EDGES + e];
            s_rel[tid] = fabsf(last_update[sn] - t[e]);
        } else {
            s_src[tid] = 0; s_dst[tid] = 0; s_rel[tid] = 0.f;
        }
    }
    __syncthreads();

    // stage edge_attr: thread handles edge j = tid>>2, 32 cols (seg = tid&3)
    {
        int j = tid >> 2, seg = tid & 3, k0 = seg * 32;
        size_t e = e0 + j;
        bool valid = (e < N_EDGES);
        float vals[32];
        if (seg < 2) {
            if (valid) {
                const float4* mp = (const float4*)(msg + e * EDGEF + k0);
#pragma unroll
                for (int i = 0; i < 8; i++) {
                    float4 a = mp[i];
                    vals[4 * i] = a.x; vals[4 * i + 1] = a.y;
                    vals[4 * i + 2] = a.z; vals[4 * i + 3] = a.w;
                }
            } else {
#pragma unroll
                for (int i = 0; i < 32; i++) vals[i] = 0.f;
            }
        } else {
            int td = k0 - 64;
            float rel = s_rel[j];
            const float4* wtp = (const float4*)(w_time + td);
            const float4* btp = (const float4*)(b_time + td);
#pragma unroll
            for (int i = 0; i < 8; i++) {
                float4 wt = wtp[i];
                float4 bt = btp[i];
                vals[4 * i]     = valid ? __cosf(rel * wt.x + bt.x) : 0.f;
                vals[4 * i + 1] = valid ? __cosf(rel * wt.y + bt.y) : 0.f;
                vals[4 * i + 2] = valid ? __cosf(rel * wt.z + bt.z) : 0.f;
                vals[4 * i + 3] = valid ? __cosf(rel * wt.w + bt.w) : 0.f;
            }
        }
        unsigned int* dp = (unsigned int*)&sE[j][k0];
#pragma unroll
        for (int i = 0; i < 16; i++) {
            unsigned int lo = (unsigned short)f2bs(vals[2 * i]);
            unsigned int hi = (unsigned short)f2bs(vals[2 * i + 1]);
            dp[i] = lo | (hi << 16);
        }
    }
    __syncthreads();

    const int wave = tid >> 6, lane = tid & 63;
    const int quad = lane >> 4, l16 = lane & 15;

    // MFMA: wave w computes ep rows w*16..w*16+15 (its OWN edges), all 128 cols.
    // B-fragments straight from global Web (32KB, cache-resident).
    f32x4 acc[8];
#pragma unroll
    for (int i = 0; i < 8; i++) acc[i] = (f32x4){0.f, 0.f, 0.f, 0.f};
#pragma unroll
    for (int ko = 0; ko < 4; ko++) {
        bf16x8 a = *(const bf16x8*)&sE[wave * 16 + l16][ko * 32 + quad * 8];
#pragma unroll
        for (int i = 0; i < 8; i++) {
            bf16x8 b = *(const bf16x8*)(Web + (size_t)(i * 16 + l16) * D_EDGE + ko * 32 + quad * 8);
            acc[i] = __builtin_amdgcn_mfma_f32_16x16x32_bf16(a, b, acc[i], 0, 0, 0);
        }
    }
    __syncthreads();   // all sE(edge_attr) reads complete before overwrite with ep
#pragma unroll
    for (int i = 0; i < 8; i++)
#pragma unroll
        for (int r = 0; r < 4; r++)
            sE[wave * 16 + quad * 4 + r][i * 16 + l16] = f2bs(acc[i][r]);
    __syncthreads();

    // Tail: wave w owns edges w*16..w*16+15. Lane l handles dims {l, l+64}.
    // N_EDGES%16==0 and ranges 16-aligned -> validity per-wave all-or-nothing.
    const int base = wave * 16;
    const int d0 = lane, d1 = lane + 64;
    if (e0 + base < N_EDGES) {
        for (int jj = 0; jj < 16; jj += 2) {
            int ja = base + jj, jb = ja + 1;
            int sa = s_src[ja], da = s_dst[ja];
            int sb = s_src[jb], db = s_dst[jb];
            float epa0 = bs2f(sE[ja][d0]), epa1 = bs2f(sE[ja][d1]);
            float epb0 = bs2f(sE[jb][d0]), epb1 = bs2f(sE[jb][d1]);
            float qa0 = bs2f((short)q[(size_t)da * MEM + d0]);
            float qa1 = bs2f((short)q[(size_t)da * MEM + d1]);
            float qb0 = bs2f((short)q[(size_t)db * MEM + d0]);
            float qb1 = bs2f((short)q[(size_t)db * MEM + d1]);
            float ka0 = bs2f((short)k[(size_t)sa * MEM + d0]) + epa0;
            float ka1 = bs2f((short)k[(size_t)sa * MEM + d1]) + epa1;
            float kb0 = bs2f((short)k[(size_t)sb * MEM + d0]) + epb0;
            float kb1 = bs2f((short)k[(size_t)sb * MEM + d1]) + epb1;
            float pa = qa0 * ka0 + qa1 * ka1;
            float pb = qb0 * kb0 + qb1 * kb1;
#pragma unroll
            for (int off = 1; off < 64; off <<= 1) {
                pa += __shfl_xor(pa, off, 64);
                pb += __shfl_xor(pb, off, 64);
            }
            float exa = __expf(pa * SCALE);
            float exb = __expf(pb * SCALE);
            float va0 = bs2f((short)v[(size_t)sa * MEM + d0]) + epa0;
            float va1 = bs2f((short)v[(size_t)sa * MEM + d1]) + epa1;
            float vb0 = bs2f((short)v[(size_t)sb * MEM + d0]) + epb0;
            float vb1 = bs2f((short)v[(size_t)sb * MEM + d1]) + epb1;
            unsafeAtomicAdd(&agg[(size_t)da * MEM + d0], exa * va0);
            unsafeAtomicAdd(&agg[(size_t)da * MEM + d1], exa * va1);
            unsafeAtomicAdd(&agg[(size_t)db * MEM + d0], exb * vb0);
            unsafeAtomicAdd(&agg[(size_t)db * MEM + d1], exb * vb1);
            if (lane == 0) {
                unsafeAtomicAdd(&denom[da], exa);
                unsafeAtomicAdd(&denom[db], exb);
            }
        }
    }
}

__global__ __launch_bounds__(128) void k_final(
    const float* __restrict__ h, const float* __restrict__ agg,
    const float* __restrict__ denom, const float* __restrict__ Abuf,
    const float* __restrict__ b_anti, float* __restrict__ out)
{
    __shared__ float hsh[NPB][MEM];
    const int m = threadIdx.x;
    const int n0 = blockIdx.x * NPB;
    for (int j = 0; j < NPB; j++) hsh[j][m] = h[(size_t)(n0 + j) * MEM + m];
    __syncthreads();
    float acc[NPB];
    float ba = b_anti[m];
    for (int j = 0; j < NPB; j++) {
        float dn = denom[n0 + j] + 1e-16f;
        acc[j] = ba + agg[(size_t)(n0 + j) * MEM + m] / dn;
    }
    const float4* A4 = (const float4*)(Abuf + (size_t)m * MEM);
    for (int d4 = 0; d4 < MEM / 4; d4++) {
        float4 w = A4[d4];
        int d = d4 * 4;
        for (int j = 0; j < NPB; j++)
            acc[j] += w.x * hsh[j][d] + w.y * hsh[j][d + 1] + w.z * hsh[j][d + 2] + w.w * hsh[j][d + 3];
    }
    for (int j = 0; j < NPB; j++) {
        float hv = hsh[j][m] + EPSILON * tanhf(acc[j]);
        out[(size_t)(n0 + j) * MEM + m] = tanhf(hv);
    }
}

extern "C" void kernel_launch(void* const* d_in, const int* in_sizes, int n_in,
                              void* d_out, int out_size, void* d_ws, size_t ws_size,
                              hipStream_t stream) {
    const float* x          = (const float*)d_in[0];
    const float* last_update= (const float*)d_in[1];
    const int*   ei         = (const int*)  d_in[2];
    const float* t          = (const float*)d_in[3];
    const float* msg        = (const float*)d_in[4];
    const float* w_time     = (const float*)d_in[5];
    const float* b_time     = (const float*)d_in[6];
    const float* W_enc      = (const float*)d_in[7];
    const float* b_enc      = (const float*)d_in[8];
    const float* Wq         = (const float*)d_in[9];
    const float* bq         = (const float*)d_in[10];
    const float* Wk         = (const float*)d_in[11];
    const float* bk         = (const float*)d_in[12];
    const float* Wv         = (const float*)d_in[13];
    const float* bv         = (const float*)d_in[14];
    const float* We         = (const float*)d_in[15];
    const float* W_anti     = (const float*)d_in[16];
    const float* b_anti     = (const float*)d_in[17];
    float* out = (float*)d_out;

    float* ws = (float*)d_ws;
    size_t nm = (size_t)N_NODES * MEM;
    float* h     = ws;                 // N*128 fp32
    float* agg   = h + nm;             // N*128 fp32
    float* denom = agg + nm;           // N fp32
    float* Abuf  = denom + N_NODES;    // 128*128 fp32
    unsigned short* qb    = (unsigned short*)(Abuf + MEM * MEM);  // N*128 bf16
    unsigned short* kb    = qb + nm;        // N*128 bf16
    unsigned short* vb    = kb + nm;        // N*128 bf16
    unsigned short* Web   = vb + nm;        // 16384
    unsigned short* WencH = Web + 16384;    // 32768
    unsigned short* WencL = WencH + 32768;  // 32768
    unsigned short* Wqb   = WencL + 32768;  // 16384
    unsigned short* Wkb   = Wqb + 16384;    // 16384
    unsigned short* Wvb   = Wkb + 16384;    // 16384

    hipMemsetAsync(agg, 0, (nm + N_NODES) * sizeof(float), stream);
    k_prep<<<128, 256, 0, stream>>>(W_anti, We, W_enc, Wq, Wk, Wv,
                                    Abuf, Web, WencH, WencL, Wqb, Wkb, Wvb);

    k_node_proj<<<N_NODES / NT, 256, 0, stream>>>(
        x, b_enc, bq, bk, bv, WencH, WencL, Wqb, Wkb, Wvb, h, qb, kb, vb);

    k_edge_all<<<(N_EDGES + ET - 1) / ET, 256, 0, stream>>>(
        ei, last_update, t, msg, w_time, b_time, Web, qb, kb, vb, agg, denom);

    k_final<<<N_NODES / NPB, 128, 0, stream>>>(h, agg, denom, Abuf, b_anti, out);
}

// Round 5
// 806.458 us; speedup vs baseline: 1.3423x; 1.0756x over previous
//
#include <hip/hip_runtime.h>
#include <hip/hip_bf16.h>
#include <math.h>

#define N_NODES 100000
#define N_EDGES 500000
#define MEM 128
#define IN_DIM 256
#define EDGEF 64
#define D_EDGE 128
#define EPSILON 0.1f
#define GAMMA 0.1f
#define SCALE 0.08838834764831845f  // 1/sqrt(128)

#define NPB 8     // nodes per block in k_final
#define NT 32     // nodes per block in k_node_proj (100000/32 = 3125)
#define XP 264    // padded LDS row for x bf16 tile (shorts)
#define HP 136    // padded LDS row for h bf16 tile (shorts)
#define ET 64     // edges per block in k_edge_all
#define EA_LD 200 // padded LDS row for bf16 edge tile (stride 400B ≡ 4 mod 32
                  // dwords — conflict-free; sized so LDS ~26.4KB -> 6 blocks/CU:
                  // measured optimum between 4 (under-hides) and 8 (L2 thrash))

typedef __attribute__((ext_vector_type(8))) short bf16x8;
typedef __attribute__((ext_vector_type(4))) float f32x4;

__device__ __forceinline__ short f2bs(float f) {
    __hip_bfloat16 b = __float2bfloat16(f);
    return *(short*)&b;
}
__device__ __forceinline__ float bs2f(short s) {
    __hip_bfloat16 b = *(__hip_bfloat16*)&s;
    return __bfloat162float(b);
}
// unpack 2 bf16 (packed in a uint) to floats — exact, 2 VALU ops
__device__ __forceinline__ float2 up2(unsigned int u) {
    float2 r;
    r.x = __uint_as_float(u << 16);
    r.y = __uint_as_float(u & 0xffff0000u);
    return r;
}
__device__ __forceinline__ unsigned int pk2(float lo, float hi) {
    return (unsigned int)(unsigned short)f2bs(lo)
         | ((unsigned int)(unsigned short)f2bs(hi) << 16);
}
// HW packed bf16 atomic add (gfx950). One dword per lane, wave-contiguous.
__device__ __forceinline__ void atomic_pk_add_bf16(unsigned short* addr, unsigned int data) {
    asm volatile("global_atomic_pk_add_bf16 %0, %1, off"
                 :: "v"(addr), "v"(data) : "memory");
}

// Abuf = W_anti - W_anti^T - gamma*I; bf16 copies of We, Wq, Wk, Wv;
// hi/lo bf16 split of W_enc.
__global__ void k_prep(const float* __restrict__ W_anti, const float* __restrict__ We,
                       const float* __restrict__ W_enc,
                       const float* __restrict__ Wq, const float* __restrict__ Wk,
                       const float* __restrict__ Wv,
                       float* __restrict__ Abuf, unsigned short* __restrict__ Web,
                       unsigned short* __restrict__ WencH, unsigned short* __restrict__ WencL,
                       unsigned short* __restrict__ Wqb, unsigned short* __restrict__ Wkb,
                       unsigned short* __restrict__ Wvb) {
    int idx = blockIdx.x * blockDim.x + threadIdx.x;  // 0..32767
    float w = W_enc[idx];
    short hi = f2bs(w);
    WencH[idx] = (unsigned short)hi;
    WencL[idx] = (unsigned short)f2bs(w - bs2f(hi));
    if (idx < 16384) {
        int m = idx >> 7, d = idx & 127;
        float a = W_anti[m * 128 + d] - W_anti[d * 128 + m];
        if (m == d) a -= GAMMA;
        Abuf[idx] = a;
        Web[idx] = (unsigned short)f2bs(We[idx]);
        Wqb[idx] = (unsigned short)f2bs(Wq[idx]);
        Wkb[idx] = (unsigned short)f2bs(Wk[idx]);
        Wvb[idx] = (unsigned short)f2bs(Wv[idx]);
    }
}

// MFMA node projections. h = x@W_enc^T + b_enc via split-precision bf16
// (x_hi*W_hi + x_lo*W_hi + x_hi*W_lo ~ fp32 accuracy — h feeds out undamped).
// q,k,v = h@W^T + b via plain bf16, STORED AS BF16 (halves edge-phase gather
// traffic; errors damped by softmax normalization + eps*tanh downstream).
__global__ __launch_bounds__(256) void k_node_proj(
    const float* __restrict__ x,
    const float* __restrict__ b_enc, const float* __restrict__ bq,
    const float* __restrict__ bk, const float* __restrict__ bv,
    const unsigned short* __restrict__ WencH, const unsigned short* __restrict__ WencL,
    const unsigned short* __restrict__ Wqb, const unsigned short* __restrict__ Wkb,
    const unsigned short* __restrict__ Wvb,
    float* __restrict__ h, unsigned short* __restrict__ q,
    unsigned short* __restrict__ k, unsigned short* __restrict__ v)
{
    __shared__ short xhi[NT][XP];
    __shared__ short xlo[NT][XP];
    __shared__ short hb[NT][HP];
    const int tid = threadIdx.x;
    const int n0 = blockIdx.x * NT;

    // stage x tile -> hi/lo bf16 LDS
    {
        int r = tid >> 3, seg = tid & 7;  // 32 rows x 8 segs of 32 cols
        const float4* xp = (const float4*)(x + (size_t)(n0 + r) * IN_DIM + seg * 32);
        unsigned int* dh = (unsigned int*)&xhi[r][seg * 32];
        unsigned int* dl = (unsigned int*)&xlo[r][seg * 32];
#pragma unroll
        for (int i = 0; i < 8; i++) {
            float4 a = xp[i];
            float fs[4] = {a.x, a.y, a.z, a.w};
            unsigned short h2[4], l2[4];
#pragma unroll
            for (int j = 0; j < 4; j++) {
                short hbit = f2bs(fs[j]);
                h2[j] = (unsigned short)hbit;
                l2[j] = (unsigned short)f2bs(fs[j] - bs2f(hbit));
            }
            dh[2 * i]     = h2[0] | ((unsigned int)h2[1] << 16);
            dh[2 * i + 1] = h2[2] | ((unsigned int)h2[3] << 16);
            dl[2 * i]     = l2[0] | ((unsigned int)l2[1] << 16);
            dl[2 * i + 1] = l2[2] | ((unsigned int)l2[3] << 16);
        }
    }
    __syncthreads();

    const int wave = tid >> 6, lane = tid & 63;
    const int quad = lane >> 4, l16 = lane & 15;
    const int mt = wave & 1;       // 16-node half
    const int nh = wave >> 1;      // 64-col half

    // h: 3-term split-precision MFMA over K=256
    f32x4 acc[4];
#pragma unroll
    for (int i = 0; i < 4; i++) acc[i] = (f32x4){0.f, 0.f, 0.f, 0.f};
#pragma unroll
    for (int ko = 0; ko < 8; ko++) {
        bf16x8 ah = *(const bf16x8*)&xhi[mt * 16 + l16][ko * 32 + quad * 8];
        bf16x8 al = *(const bf16x8*)&xlo[mt * 16 + l16][ko * 32 + quad * 8];
#pragma unroll
        for (int i = 0; i < 4; i++) {
            size_t boff = (size_t)(nh * 64 + i * 16 + l16) * IN_DIM + ko * 32 + quad * 8;
            bf16x8 bh = *(const bf16x8*)(WencH + boff);
            bf16x8 bl = *(const bf16x8*)(WencL + boff);
            acc[i] = __builtin_amdgcn_mfma_f32_16x16x32_bf16(ah, bh, acc[i], 0, 0, 0);
            acc[i] = __builtin_amdgcn_mfma_f32_16x16x32_bf16(al, bh, acc[i], 0, 0, 0);
            acc[i] = __builtin_amdgcn_mfma_f32_16x16x32_bf16(ah, bl, acc[i], 0, 0, 0);
        }
    }
#pragma unroll
    for (int i = 0; i < 4; i++) {
        int col = nh * 64 + i * 16 + l16;
        float be = b_enc[col];
#pragma unroll
        for (int r = 0; r < 4; r++) {
            int row = mt * 16 + quad * 4 + r;
            float hv = acc[i][r] + be;
            h[(size_t)(n0 + row) * MEM + col] = hv;
            hb[row][col] = f2bs(hv);
        }
    }
    __syncthreads();

#define QKV(Wb, BIAS, OUT)                                                        \
    {                                                                             \
        f32x4 a2[4];                                                              \
        for (int i = 0; i < 4; i++) a2[i] = (f32x4){0.f, 0.f, 0.f, 0.f};          \
        for (int ko = 0; ko < 4; ko++) {                                          \
            bf16x8 a = *(const bf16x8*)&hb[mt * 16 + l16][ko * 32 + quad * 8];    \
            for (int i = 0; i < 4; i++) {                                         \
                size_t boff = (size_t)(nh * 64 + i * 16 + l16) * MEM              \
                            + ko * 32 + quad * 8;                                 \
                bf16x8 b = *(const bf16x8*)(Wb + boff);                           \
                a2[i] = __builtin_amdgcn_mfma_f32_16x16x32_bf16(a, b, a2[i], 0, 0, 0); \
            }                                                                     \
        }                                                                         \
        for (int i = 0; i < 4; i++) {                                             \
            int col = nh * 64 + i * 16 + l16;                                     \
            float bb = BIAS[col];                                                 \
            for (int r = 0; r < 4; r++) {                                         \
                int row = mt * 16 + quad * 4 + r;                                 \
                OUT[(size_t)(n0 + row) * MEM + col] =                             \
                    (unsigned short)f2bs(a2[i][r] + bb);                          \
            }                                                                     \
        }                                                                         \
    }
    QKV(Wqb, bq, q)
    QKV(Wkb, bk, k)
    QKV(Wvb, bv, v)
#undef QKV
}

// One pass over 64 edges per block: build edge_attr (bf16 LDS), e_proj via
// MFMA with B-fragments read directly from global Web (L1/L2-resident),
// ep stored back as BF16 into the SAME LDS buffer.
// Tail: ONE WAVE PER EDGE — lane l owns ADJACENT dims {2l, 2l+1}:
//  - gathers: one uint (packed bf16x2) per array per edge -> 256B/wave contiguous
//  - agg update: ONE global_atomic_pk_add_bf16 per lane per edge ->
//    256B/wave contiguous, HALF the atomic ops & dirty bytes of fp32 dims
//    (R4 measured 192G atomics/s ~ at the L2 atomic-pipe ceiling; WRITE was
//    7x the final agg state from line churn).
// No barriers in tail; 2-edge ILP unroll.
__global__ __launch_bounds__(256, 6) void k_edge_all(
    const int* __restrict__ ei, const float* __restrict__ last_update,
    const float* __restrict__ t, const float* __restrict__ msg,
    const float* __restrict__ w_time, const float* __restrict__ b_time,
    const unsigned short* __restrict__ Web,
    const unsigned short* __restrict__ q, const unsigned short* __restrict__ k,
    const unsigned short* __restrict__ v,
    unsigned short* __restrict__ agg, float* __restrict__ denom)
{
    __shared__ short sE[ET][EA_LD];   // bf16 edge_attr, then overwritten with bf16 ep
    __shared__ int s_src[ET], s_dst[ET];
    __shared__ float s_rel[ET];

    const int tid = threadIdx.x;
    const size_t e0 = (size_t)blockIdx.x * ET;

    if (tid < ET) {
        size_t e = e0 + tid;
        if (e < N_EDGES) {
            int sn = ei[e];
            s_src[tid] = sn;
            s_dst[tid] = ei[N_EDGES + e];
            s_rel[tid] = fabsf(last_update[sn] - t[e]);
        } else {
            s_src[tid] = 0; s_dst[tid] = 0; s_rel[tid] = 0.f;
        }
    }
    __syncthreads();

    // stage edge_attr: thread handles edge j = tid>>2, 32 cols (seg = tid&3)
    {
        int j = tid >> 2, seg = tid & 3, k0 = seg * 32;
        size_t e = e0 + j;
        bool valid = (e < N_EDGES);
        float vals[32];
        if (seg < 2) {
            if (valid) {
                const float4* mp = (const float4*)(msg + e * EDGEF + k0);
#pragma unroll
                for (int i = 0; i < 8; i++) {
                    float4 a = mp[i];
                    vals[4 * i] = a.x; vals[4 * i + 1] = a.y;
                    vals[4 * i + 2] = a.z; vals[4 * i + 3] = a.w;
                }
            } else {
#pragma unroll
                for (int i = 0; i < 32; i++) vals[i] = 0.f;
            }
        } else {
            int td = k0 - 64;
            float rel = s_rel[j];
            const float4* wtp = (const float4*)(w_time + td);
            const float4* btp = (const float4*)(b_time + td);
#pragma unroll
            for (int i = 0; i < 8; i++) {
                float4 wt = wtp[i];
                float4 bt = btp[i];
                vals[4 * i]     = valid ? __cosf(rel * wt.x + bt.x) : 0.f;
                vals[4 * i + 1] = valid ? __cosf(rel * wt.y + bt.y) : 0.f;
                vals[4 * i + 2] = valid ? __cosf(rel * wt.z + bt.z) : 0.f;
                vals[4 * i + 3] = valid ? __cosf(rel * wt.w + bt.w) : 0.f;
            }
        }
        unsigned int* dp = (unsigned int*)&sE[j][k0];
#pragma unroll
        for (int i = 0; i < 16; i++) {
            unsigned int lo = (unsigned short)f2bs(vals[2 * i]);
            unsigned int hi = (unsigned short)f2bs(vals[2 * i + 1]);
            dp[i] = lo | (hi << 16);
        }
    }
    __syncthreads();

    const int wave = tid >> 6, lane = tid & 63;
    const int quad = lane >> 4, l16 = lane & 15;

    // MFMA: wave w computes ep rows w*16..w*16+15 (its OWN edges), all 128 cols.
    // B-fragments straight from global Web (32KB, cache-resident).
    f32x4 acc[8];
#pragma unroll
    for (int i = 0; i < 8; i++) acc[i] = (f32x4){0.f, 0.f, 0.f, 0.f};
#pragma unroll
    for (int ko = 0; ko < 4; ko++) {
        bf16x8 a = *(const bf16x8*)&sE[wave * 16 + l16][ko * 32 + quad * 8];
#pragma unroll
        for (int i = 0; i < 8; i++) {
            bf16x8 b = *(const bf16x8*)(Web + (size_t)(i * 16 + l16) * D_EDGE + ko * 32 + quad * 8);
            acc[i] = __builtin_amdgcn_mfma_f32_16x16x32_bf16(a, b, acc[i], 0, 0, 0);
        }
    }
    __syncthreads();   // all sE(edge_attr) reads complete before overwrite with ep
#pragma unroll
    for (int i = 0; i < 8; i++)
#pragma unroll
        for (int r = 0; r < 4; r++)
            sE[wave * 16 + quad * 4 + r][i * 16 + l16] = f2bs(acc[i][r]);
    __syncthreads();

    // Tail: wave w owns edges w*16..w*16+15. Lane l handles dims {2l, 2l+1}.
    // N_EDGES%16==0 and ranges 16-aligned -> validity per-wave all-or-nothing.
    const int base = wave * 16;
    const int d2 = lane * 2;
    if (e0 + base < N_EDGES) {
        for (int jj = 0; jj < 16; jj += 2) {
            int ja = base + jj, jb = ja + 1;
            int sa = s_src[ja], da = s_dst[ja];
            int sb = s_src[jb], db = s_dst[jb];
            float2 epa = up2(*(const unsigned int*)&sE[ja][d2]);
            float2 epb = up2(*(const unsigned int*)&sE[jb][d2]);
            float2 qa = up2(*(const unsigned int*)(q + (size_t)da * MEM + d2));
            float2 qb2 = up2(*(const unsigned int*)(q + (size_t)db * MEM + d2));
            float2 ka = up2(*(const unsigned int*)(k + (size_t)sa * MEM + d2));
            float2 kb2 = up2(*(const unsigned int*)(k + (size_t)sb * MEM + d2));
            float pa = qa.x * (ka.x + epa.x) + qa.y * (ka.y + epa.y);
            float pb = qb2.x * (kb2.x + epb.x) + qb2.y * (kb2.y + epb.y);
#pragma unroll
            for (int off = 1; off < 64; off <<= 1) {
                pa += __shfl_xor(pa, off, 64);
                pb += __shfl_xor(pb, off, 64);
            }
            float exa = __expf(pa * SCALE);
            float exb = __expf(pb * SCALE);
            float2 va = up2(*(const unsigned int*)(v + (size_t)sa * MEM + d2));
            float2 vb = up2(*(const unsigned int*)(v + (size_t)sb * MEM + d2));
            unsigned int pka = pk2(exa * (va.x + epa.x), exa * (va.y + epa.y));
            unsigned int pkb = pk2(exb * (vb.x + epb.x), exb * (vb.y + epb.y));
            atomic_pk_add_bf16(agg + (size_t)da * MEM + d2, pka);
            atomic_pk_add_bf16(agg + (size_t)db * MEM + d2, pkb);
            if (lane == 0) {
                unsafeAtomicAdd(&denom[da], exa);
                unsafeAtomicAdd(&denom[db], exb);
            }
        }
    }
}

__global__ __launch_bounds__(128) void k_final(
    const float* __restrict__ h, const unsigned short* __restrict__ agg,
    const float* __restrict__ denom, const float* __restrict__ Abuf,
    const float* __restrict__ b_anti, float* __restrict__ out)
{
    __shared__ float hsh[NPB][MEM];
    const int m = threadIdx.x;
    const int n0 = blockIdx.x * NPB;
    for (int j = 0; j < NPB; j++) hsh[j][m] = h[(size_t)(n0 + j) * MEM + m];
    __syncthreads();
    float acc[NPB];
    float ba = b_anti[m];
    for (int j = 0; j < NPB; j++) {
        float dn = denom[n0 + j] + 1e-16f;
        float ag = bs2f((short)agg[(size_t)(n0 + j) * MEM + m]);
        acc[j] = ba + ag / dn;
    }
    const float4* A4 = (const float4*)(Abuf + (size_t)m * MEM);
    for (int d4 = 0; d4 < MEM / 4; d4++) {
        float4 w = A4[d4];
        int d = d4 * 4;
        for (int j = 0; j < NPB; j++)
            acc[j] += w.x * hsh[j][d] + w.y * hsh[j][d + 1] + w.z * hsh[j][d + 2] + w.w * hsh[j][d + 3];
    }
    for (int j = 0; j < NPB; j++) {
        float hv = hsh[j][m] + EPSILON * tanhf(acc[j]);
        out[(size_t)(n0 + j) * MEM + m] = tanhf(hv);
    }
}

extern "C" void kernel_launch(void* const* d_in, const int* in_sizes, int n_in,
                              void* d_out, int out_size, void* d_ws, size_t ws_size,
                              hipStream_t stream) {
    const float* x          = (const float*)d_in[0];
    const float* last_update= (const float*)d_in[1];
    const int*   ei         = (const int*)  d_in[2];
    const float* t          = (const float*)d_in[3];
    const float* msg        = (const float*)d_in[4];
    const float* w_time     = (const float*)d_in[5];
    const float* b_time     = (const float*)d_in[6];
    const float* W_enc      = (const float*)d_in[7];
    const float* b_enc      = (const float*)d_in[8];
    const float* Wq         = (const float*)d_in[9];
    const float* bq         = (const float*)d_in[10];
    const float* Wk         = (const float*)d_in[11];
    const float* bk         = (const float*)d_in[12];
    const float* Wv         = (const float*)d_in[13];
    const float* bv         = (const float*)d_in[14];
    const float* We         = (const float*)d_in[15];
    const float* W_anti     = (const float*)d_in[16];
    const float* b_anti     = (const float*)d_in[17];
    float* out = (float*)d_out;

    float* ws = (float*)d_ws;
    size_t nm = (size_t)N_NODES * MEM;
    float* h     = ws;                        // N*128 fp32
    float* Abuf  = h + nm;                    // 128*128 fp32
    unsigned short* agg = (unsigned short*)(Abuf + MEM * MEM);  // N*128 bf16
    float* denom = (float*)(agg + nm);        // N fp32 (nm*2 bytes is 4B-aligned)
    unsigned short* qb    = (unsigned short*)(denom + N_NODES); // N*128 bf16
    unsigned short* kb    = qb + nm;          // N*128 bf16
    unsigned short* vb    = kb + nm;          // N*128 bf16
    unsigned short* Web   = vb + nm;          // 16384
    unsigned short* WencH = Web + 16384;      // 32768
    unsigned short* WencL = WencH + 32768;    // 32768
    unsigned short* Wqb   = WencL + 32768;    // 16384
    unsigned short* Wkb   = Wqb + 16384;      // 16384
    unsigned short* Wvb   = Wkb + 16384;      // 16384

    // agg (bf16, zeros are 0x0000) and denom (fp32) are adjacent: one memset
    hipMemsetAsync(agg, 0, nm * sizeof(unsigned short) + N_NODES * sizeof(float), stream);
    k_prep<<<128, 256, 0, stream>>>(W_anti, We, W_enc, Wq, Wk, Wv,
                                    Abuf, Web, WencH, WencL, Wqb, Wkb, Wvb);

    k_node_proj<<<N_NODES / NT, 256, 0, stream>>>(
        x, b_enc, bq, bk, bv, WencH, WencL, Wqb, Wkb, Wvb, h, qb, kb, vb);

    k_edge_all<<<(N_EDGES + ET - 1) / ET, 256, 0, stream>>>(
        ei, last_update, t, msg, w_time, b_time, Web, qb, kb, vb, agg, denom);

    k_final<<<N_NODES / NPB, 128, 0, stream>>>(h, agg, denom, Abuf, b_anti, out);
}